// Round 2
// baseline (2180.157 us; speedup 1.0000x reference)
//
#include <hip/hip_runtime.h>
#include <cstdint>

using u16 = unsigned short;
using u32 = unsigned int;

typedef _Float16 h8 __attribute__((ext_vector_type(8)));
typedef _Float16 h4 __attribute__((ext_vector_type(4)));
typedef float f32x4 __attribute__((ext_vector_type(4)));

#define N_PER_B 175
#define NN 22400
#define DCOL 1024

// async global->LDS, 16B per lane; LDS dst is wave-uniform base + lane*16
__device__ __forceinline__ void gload16(const void* g, void* l) {
  void* gnc = const_cast<void*>(g);
  __builtin_amdgcn_global_load_lds(
      (__attribute__((address_space(1))) unsigned int*)gnc,
      (__attribute__((address_space(3))) unsigned int*)l, 16, 0, 0);
}

// ---------------- degree / CSR build ----------------

__global__ void degree_k(const int* __restrict__ es, const int* __restrict__ ed,
                         u32* __restrict__ dout, u32* __restrict__ din, int nE) {
  int e = blockIdx.x * 256 + threadIdx.x;
  if (e < nE) {
    atomicAdd(&dout[es[e]], 1u);
    atomicAdd(&din[ed[e]], 1u);
  }
}

__global__ void dinv_k(const u32* __restrict__ dout, const u32* __restrict__ din,
                       float* __restrict__ vo, float* __restrict__ vi) {
  int i = blockIdx.x * 256 + threadIdx.x;
  if (i < NN) {
    u32 a = dout[i]; if (a == 0u) a = 1u;
    u32 b = din[i];  if (b == 0u) b = 1u;
    vo[i] = rsqrtf((float)a);
    vi[i] = rsqrtf((float)b);
  }
}

// single-block scan, wave-shuffle based: 2 barriers per 1024-chunk
__global__ __launch_bounds__(1024) void scan_k(const u32* __restrict__ deg,
                                               u32* __restrict__ off, int n) {
  __shared__ u32 wsum[16];
  __shared__ u32 carry_s;
  int tid = threadIdx.x;
  int lane = tid & 63, w = tid >> 6;
  if (tid == 0) carry_s = 0u;
  __syncthreads();
  for (int base = 0; base < n; base += 1024) {
    u32 cb = carry_s;                      // consistent (post prior sync B)
    int i = base + tid;
    u32 v = (i < n) ? deg[i] : 0u;
    u32 x = v;
#pragma unroll
    for (int o = 1; o < 64; o <<= 1) {     // wave inclusive scan
      u32 t = __shfl_up(x, o);
      if (lane >= o) x += t;
    }
    if (lane == 63) wsum[w] = x;
    __syncthreads();                       // A: wsum visible
    u32 woff = 0;
#pragma unroll
    for (int j = 0; j < 16; ++j) { u32 s = wsum[j]; if (j < w) woff += s; }
    u32 incl = cb + woff + x;
    if (i < n) off[i] = incl - v;          // exclusive
    if (tid == 1023) carry_s = incl;
    __syncthreads();                       // B: carry visible, wsum reads done
  }
  if (tid == 0) off[n] = carry_s;
}

__global__ void scatter_k(const int* __restrict__ es, const int* __restrict__ ed,
                          const u32* __restrict__ off, u32* __restrict__ cur,
                          int* __restrict__ csr, int nE) {
  int e = blockIdx.x * 256 + threadIdx.x;
  if (e < nE) {
    int d = ed[e];
    u32 p = atomicAdd(&cur[d], 1u);
    csr[off[d] + p] = es[e];
  }
}

// ---------------- concat + layernorm -> fp16 node matrix ----------------

__global__ __launch_bounds__(256) void ln_k(const float* __restrict__ mh,
    const float* __restrict__ eh, const float* __restrict__ sh,
    const float* __restrict__ te, const float* __restrict__ sc,
    const float* __restrict__ bi, _Float16* __restrict__ x0) {
  int node = blockIdx.x;
  int b = node / N_PER_B;
  int p = node - b * N_PER_B;
  const float* row;
  int t;
  if (p < 100)      { row = mh + ((size_t)b * 100 + p) * 768;        t = 0; }
  else if (p < 150) { row = eh + ((size_t)b * 50 + (p - 100)) * 768; t = 1; }
  else              { row = sh + ((size_t)b * 25 + (p - 150)) * 768; t = 2; }
  int tid = threadIdx.x;
  const float* lp = (tid < 192) ? (row + tid * 4) : (te + t * 256 + (tid - 192) * 4);
  float4 v = *(const float4*)lp;
  float s = v.x + v.y + v.z + v.w;
  float q = v.x * v.x + v.y * v.y + v.z * v.z + v.w * v.w;
#pragma unroll
  for (int o = 32; o > 0; o >>= 1) { s += __shfl_down(s, o); q += __shfl_down(q, o); }
  __shared__ float red[8];
  int w = tid >> 6;
  if ((tid & 63) == 0) { red[w] = s; red[4 + w] = q; }
  __syncthreads();
  float ts = red[0] + red[1] + red[2] + red[3];
  float tq = red[4] + red[5] + red[6] + red[7];
  float mu = ts * (1.0f / 1024.0f);
  float var = tq * (1.0f / 1024.0f) - mu * mu;
  float r = rsqrtf(var + 1e-5f);
  int c = tid * 4;
  float4 g  = *(const float4*)(sc + c);
  float4 hb = *(const float4*)(bi + c);
  h4 o;
  o.x = (_Float16)((v.x - mu) * r * g.x + hb.x);
  o.y = (_Float16)((v.y - mu) * r * g.y + hb.y);
  o.z = (_Float16)((v.z - mu) * r * g.z + hb.z);
  o.w = (_Float16)((v.w - mu) * r * g.w + hb.w);
  *(h4*)(x0 + (size_t)node * DCOL + c) = o;
}

// ---------------- weight transpose fp32 [K][N] -> fp16 [N][K] ----------------

__global__ __launch_bounds__(256) void transpose_k(const float* __restrict__ W,
    _Float16* __restrict__ Wt, int K, int N) {
  __shared__ float tile[32][33];
  int n0 = blockIdx.x * 32, k0 = blockIdx.y * 32;
  int tx = threadIdx.x & 31, ty = threadIdx.x >> 5;  // 32 x 8
#pragma unroll
  for (int i = 0; i < 32; i += 8)
    tile[ty + i][tx] = W[(size_t)(k0 + ty + i) * N + n0 + tx];
  __syncthreads();
#pragma unroll
  for (int i = 0; i < 32; i += 8)
    Wt[(size_t)(n0 + ty + i) * K + k0 + tx] = (_Float16)tile[tx][ty + i];
}

// ---------------- CSR aggregation, column-chunked for L2 residency ----------------
// One wave per (dst node, 64-col chunk); lane = column. Per-chunk random
// working set = 22400*64*2B = 2.87MB < 4MB L2/XCD -> gathers hit L2.
// agg[d] = dinv_in[d] * sum_src dinv_out[s] * x[s]

template<int ENT>
__global__ __launch_bounds__(256) void aggregate_k(const _Float16* __restrict__ x,
    const u32* __restrict__ off, const int* __restrict__ srcs,
    const float* __restrict__ dvo, const float* __restrict__ dvi,
    _Float16* __restrict__ out) {
  int wave = threadIdx.x >> 6;
  int lane = threadIdx.x & 63;
  int blk = blockIdx.x * 4 + wave;          // dst index (compact for ENT)
  int d;
  if (ENT) { int b = blk / 50; d = b * N_PER_B + 100 + (blk - b * 50); }
  else d = blk;
  int col = blockIdx.y * 64 + lane;
  u32 s0 = off[d], s1 = off[d + 1];
  float acc = 0.f;
  for (u32 s = s0; s < s1; ++s) {
    int sn = __builtin_amdgcn_readfirstlane(srcs[s]);   // scalarize addr math
    float wv = dvo[sn];
    acc += wv * (float)x[(size_t)sn * DCOL + col];
  }
  out[(size_t)blk * DCOL + col] = (_Float16)(acc * dvi[d]);
}

// ---------------- MFMA GEMM: C = A[M,K] * Bt[N,K]^T (+bias, epilogue) ----------------
// EPI 0: leaky_relu(C+bias) -> f16 out (ld N) ; EPI 1: C+bias -> f32 out (ld N)

template<int EPI>
__global__ __launch_bounds__(256, 2) void gemm_bt(const _Float16* __restrict__ A,
    const _Float16* __restrict__ Bt, const float* __restrict__ bias,
    _Float16* __restrict__ outh, float* __restrict__ outf, int N, int K) {
  __shared__ __align__(16) _Float16 sA[128 * 32];
  __shared__ __align__(16) _Float16 sB[128 * 32];
  int tid = threadIdx.x;
  int wave = tid >> 6, lane = tid & 63;
  int wm = wave & 1, wn = wave >> 1;
  int lane16 = lane & 15, quad = lane >> 4;
  int m0 = blockIdx.y * 128, n0 = blockIdx.x * 128;
  int srow  = lane >> 2;          // 0..15
  int scolb = (lane & 3) * 16;    // byte offset within 64B row
  const char* aBase = (const char*)(A  + (size_t)(m0 + wave * 32 + srow) * K) + scolb;
  const char* bBase = (const char*)(Bt + (size_t)(n0 + wave * 32 + srow) * K) + scolb;
  const size_t rowSkip = (size_t)16 * K * sizeof(_Float16);
  _Float16* lA0 = &sA[(wave * 2 + 0) * 512];
  _Float16* lA1 = &sA[(wave * 2 + 1) * 512];
  _Float16* lB0 = &sB[(wave * 2 + 0) * 512];
  _Float16* lB1 = &sB[(wave * 2 + 1) * 512];

  f32x4 acc[4][4];
  f32x4 zero = {0.f, 0.f, 0.f, 0.f};
#pragma unroll
  for (int i = 0; i < 4; ++i)
#pragma unroll
    for (int j = 0; j < 4; ++j) acc[i][j] = zero;

  for (int k0 = 0; k0 < K; k0 += 32) {
    __syncthreads();
    size_t kb = (size_t)k0 * sizeof(_Float16);
    gload16(aBase + kb,           lA0);
    gload16(aBase + kb + rowSkip, lA1);
    gload16(bBase + kb,           lB0);
    gload16(bBase + kb + rowSkip, lB1);
    __syncthreads();  // drains vmcnt before any wave reads LDS
    h8 af[4], bq[4];
#pragma unroll
    for (int mt = 0; mt < 4; ++mt)
      af[mt] = *(const h8*)&sA[(wm * 64 + mt * 16 + lane16) * 32 + quad * 8];
#pragma unroll
    for (int nt = 0; nt < 4; ++nt)
      bq[nt] = *(const h8*)&sB[(wn * 64 + nt * 16 + lane16) * 32 + quad * 8];
#pragma unroll
    for (int mt = 0; mt < 4; ++mt)
#pragma unroll
      for (int nt = 0; nt < 4; ++nt)
        acc[mt][nt] = __builtin_amdgcn_mfma_f32_16x16x32_f16(af[mt], bq[nt], acc[mt][nt], 0, 0, 0);
  }

#pragma unroll
  for (int nt = 0; nt < 4; ++nt) {
    int n = n0 + wn * 64 + nt * 16 + lane16;
    float bv = bias[n];
#pragma unroll
    for (int mt = 0; mt < 4; ++mt) {
      int mb = m0 + wm * 64 + mt * 16 + quad * 4;  // C/D: row = quad*4+i, col = lane16
#pragma unroll
      for (int i = 0; i < 4; ++i) {
        float v = acc[mt][nt][i] + bv;
        if (EPI == 0) {
          v = (v > 0.f) ? v : 0.01f * v;
          outh[(size_t)(mb + i) * N + n] = (_Float16)v;
        } else {
          outf[(size_t)(mb + i) * N + n] = v;
        }
      }
    }
  }
}

// ---------------- launch ----------------

extern "C" void kernel_launch(void* const* d_in, const int* in_sizes, int n_in,
                              void* d_out, int out_size, void* d_ws, size_t ws_size,
                              hipStream_t stream) {
  const float* mh  = (const float*)d_in[0];
  const float* eh  = (const float*)d_in[1];
  const float* sh  = (const float*)d_in[2];
  const int*   es  = (const int*)d_in[3];
  const int*   ed  = (const int*)d_in[4];
  const float* te  = (const float*)d_in[5];
  const float* lns = (const float*)d_in[6];
  const float* lnb = (const float*)d_in[7];
  const float* gw  = (const float*)d_in[8];   // [3][1024][1024]
  const float* gb  = (const float*)d_in[9];   // [3][1024]
  const float* fw  = (const float*)d_in[10];  // [1024][768]
  const float* fb  = (const float*)d_in[11];  // [768]
  float* out = (float*)d_out;                 // [128*50*768] f32
  int nE = in_sizes[3];

  char* p = (char*)d_ws;
  auto alloc = [&](size_t bytes) -> void* {
    void* r = (void*)p;
    p += (bytes + 255) & ~(size_t)255;
    return r;
  };
  _Float16* xbuf = (_Float16*)alloc((size_t)NN * DCOL * 2);
  _Float16* agg  = (_Float16*)alloc((size_t)NN * DCOL * 2);
  _Float16* wt   = (_Float16*)alloc((size_t)3 * 1024 * 1024 * 2);
  _Float16* wtfc = (_Float16*)alloc((size_t)768 * 1024 * 2);
  u32* deg_out = (u32*)alloc((size_t)NN * 4);   // these three stay contiguous
  u32* deg_in  = (u32*)alloc((size_t)NN * 4);
  u32* cursor  = (u32*)alloc((size_t)NN * 4);
  u32* csr_off = (u32*)alloc((size_t)(NN + 1) * 4);
  float* dvo = (float*)alloc((size_t)NN * 4);
  float* dvi = (float*)alloc((size_t)NN * 4);
  int* csr_src = (int*)alloc((size_t)nE * 4);

  hipMemsetAsync(deg_out, 0, (size_t)3 * NN * 4, stream);  // deg_out, deg_in, cursor

  int eb = (nE + 255) / 256;
  degree_k<<<eb, 256, 0, stream>>>(es, ed, deg_out, deg_in, nE);
  dinv_k<<<(NN + 255) / 256, 256, 0, stream>>>(deg_out, deg_in, dvo, dvi);
  scan_k<<<1, 1024, 0, stream>>>(deg_in, csr_off, NN);
  scatter_k<<<eb, 256, 0, stream>>>(es, ed, csr_off, cursor, csr_src, nE);
  ln_k<<<NN, 256, 0, stream>>>(mh, eh, sh, te, lns, lnb, xbuf);
  transpose_k<<<dim3(32, 32), 256, 0, stream>>>(gw + 0 * 1048576, wt + 0 * 1048576, 1024, 1024);
  transpose_k<<<dim3(32, 32), 256, 0, stream>>>(gw + 1 * 1048576, wt + 1 * 1048576, 1024, 1024);
  transpose_k<<<dim3(32, 32), 256, 0, stream>>>(gw + 2 * 1048576, wt + 2 * 1048576, 1024, 1024);
  transpose_k<<<dim3(24, 32), 256, 0, stream>>>(fw, wtfc, 1024, 768);

  // layer 0
  aggregate_k<0><<<dim3(5600, 16), 256, 0, stream>>>(xbuf, csr_off, csr_src, dvo, dvi, agg);
  gemm_bt<0><<<dim3(8, 175), 256, 0, stream>>>(agg, wt + 0 * 1048576, gb + 0,    xbuf, nullptr, 1024, 1024);
  // layer 1
  aggregate_k<0><<<dim3(5600, 16), 256, 0, stream>>>(xbuf, csr_off, csr_src, dvo, dvi, agg);
  gemm_bt<0><<<dim3(8, 175), 256, 0, stream>>>(agg, wt + 1 * 1048576, gb + 1024, xbuf, nullptr, 1024, 1024);
  // layer 2: only entity dst rows consumed downstream -> compact 6400 rows
  aggregate_k<1><<<dim3(1600, 16), 256, 0, stream>>>(xbuf, csr_off, csr_src, dvo, dvi, agg);
  gemm_bt<0><<<dim3(8, 50), 256, 0, stream>>>(agg, wt + 2 * 1048576, gb + 2048, xbuf, nullptr, 1024, 1024);
  // FC on compact entity rows -> d_out [6400][768] f32
  gemm_bt<1><<<dim3(6, 50), 256, 0, stream>>>(xbuf, wtfc, fb, nullptr, out, 768, 1024);
}

// Round 3
// 1161.040 us; speedup vs baseline: 1.8778x; 1.8778x over previous
//
#include <hip/hip_runtime.h>
#include <cstdint>

using u16 = unsigned short;
using u32 = unsigned int;

typedef _Float16 h8 __attribute__((ext_vector_type(8)));
typedef _Float16 h4 __attribute__((ext_vector_type(4)));
typedef float f32x4 __attribute__((ext_vector_type(4)));

#define N_PER_B 175
#define NN 22400
#define DCOL 1024

// async global->LDS, 16B per lane; LDS dst is wave-uniform base + lane*16
__device__ __forceinline__ void gload16(const void* g, void* l) {
  void* gnc = const_cast<void*>(g);
  __builtin_amdgcn_global_load_lds(
      (__attribute__((address_space(1))) unsigned int*)gnc,
      (__attribute__((address_space(3))) unsigned int*)l, 16, 0, 0);
}

// ---------------- degree / CSR build ----------------

__global__ void degree_k(const int* __restrict__ es, const int* __restrict__ ed,
                         u32* __restrict__ dout, u32* __restrict__ din, int nE) {
  int e = blockIdx.x * 256 + threadIdx.x;
  if (e < nE) {
    atomicAdd(&dout[es[e]], 1u);
    atomicAdd(&din[ed[e]], 1u);
  }
}

__global__ void dinv_k(const u32* __restrict__ dout, const u32* __restrict__ din,
                       float* __restrict__ vo, float* __restrict__ vi) {
  int i = blockIdx.x * 256 + threadIdx.x;
  if (i < NN) {
    u32 a = dout[i]; if (a == 0u) a = 1u;
    u32 b = din[i];  if (b == 0u) b = 1u;
    vo[i] = rsqrtf((float)a);
    vi[i] = rsqrtf((float)b);
  }
}

// single-block scan, wave-shuffle based: 2 barriers per 1024-chunk
__global__ __launch_bounds__(1024) void scan_k(const u32* __restrict__ deg,
                                               u32* __restrict__ off, int n) {
  __shared__ u32 wsum[16];
  __shared__ u32 carry_s;
  int tid = threadIdx.x;
  int lane = tid & 63, w = tid >> 6;
  if (tid == 0) carry_s = 0u;
  __syncthreads();
  for (int base = 0; base < n; base += 1024) {
    u32 cb = carry_s;                      // consistent (post prior sync B)
    int i = base + tid;
    u32 v = (i < n) ? deg[i] : 0u;
    u32 x = v;
#pragma unroll
    for (int o = 1; o < 64; o <<= 1) {     // wave inclusive scan
      u32 t = __shfl_up(x, o);
      if (lane >= o) x += t;
    }
    if (lane == 63) wsum[w] = x;
    __syncthreads();                       // A: wsum visible
    u32 woff = 0;
#pragma unroll
    for (int j = 0; j < 16; ++j) { u32 s = wsum[j]; if (j < w) woff += s; }
    u32 incl = cb + woff + x;
    if (i < n) off[i] = incl - v;          // exclusive
    if (tid == 1023) carry_s = incl;
    __syncthreads();                       // B: carry visible, wsum reads done
  }
  if (tid == 0) off[n] = carry_s;
}

__global__ void scatter_k(const int* __restrict__ es, const int* __restrict__ ed,
                          const u32* __restrict__ off, u32* __restrict__ cur,
                          int* __restrict__ csr, int nE) {
  int e = blockIdx.x * 256 + threadIdx.x;
  if (e < nE) {
    int d = ed[e];
    u32 p = atomicAdd(&cur[d], 1u);
    csr[off[d] + p] = es[e];
  }
}

// ---------------- concat + layernorm -> fp16 node matrix ----------------

__global__ __launch_bounds__(256) void ln_k(const float* __restrict__ mh,
    const float* __restrict__ eh, const float* __restrict__ sh,
    const float* __restrict__ te, const float* __restrict__ sc,
    const float* __restrict__ bi, _Float16* __restrict__ x0) {
  int node = blockIdx.x;
  int b = node / N_PER_B;
  int p = node - b * N_PER_B;
  const float* row;
  int t;
  if (p < 100)      { row = mh + ((size_t)b * 100 + p) * 768;        t = 0; }
  else if (p < 150) { row = eh + ((size_t)b * 50 + (p - 100)) * 768; t = 1; }
  else              { row = sh + ((size_t)b * 25 + (p - 150)) * 768; t = 2; }
  int tid = threadIdx.x;
  const float* lp = (tid < 192) ? (row + tid * 4) : (te + t * 256 + (tid - 192) * 4);
  float4 v = *(const float4*)lp;
  float s = v.x + v.y + v.z + v.w;
  float q = v.x * v.x + v.y * v.y + v.z * v.z + v.w * v.w;
#pragma unroll
  for (int o = 32; o > 0; o >>= 1) { s += __shfl_down(s, o); q += __shfl_down(q, o); }
  __shared__ float red[8];
  int w = tid >> 6;
  if ((tid & 63) == 0) { red[w] = s; red[4 + w] = q; }
  __syncthreads();
  float ts = red[0] + red[1] + red[2] + red[3];
  float tq = red[4] + red[5] + red[6] + red[7];
  float mu = ts * (1.0f / 1024.0f);
  float var = tq * (1.0f / 1024.0f) - mu * mu;
  float r = rsqrtf(var + 1e-5f);
  int c = tid * 4;
  float4 g  = *(const float4*)(sc + c);
  float4 hb = *(const float4*)(bi + c);
  h4 o;
  o.x = (_Float16)((v.x - mu) * r * g.x + hb.x);
  o.y = (_Float16)((v.y - mu) * r * g.y + hb.y);
  o.z = (_Float16)((v.z - mu) * r * g.z + hb.z);
  o.w = (_Float16)((v.w - mu) * r * g.w + hb.w);
  *(h4*)(x0 + (size_t)node * DCOL + c) = o;
}

// ---------------- weight transpose fp32 [K][N] -> fp16 [N][K] ----------------

__global__ __launch_bounds__(256) void transpose_k(const float* __restrict__ W,
    _Float16* __restrict__ Wt, int K, int N) {
  __shared__ float tile[32][33];
  int n0 = blockIdx.x * 32, k0 = blockIdx.y * 32;
  int tx = threadIdx.x & 31, ty = threadIdx.x >> 5;  // 32 x 8
#pragma unroll
  for (int i = 0; i < 32; i += 8)
    tile[ty + i][tx] = W[(size_t)(k0 + ty + i) * N + n0 + tx];
  __syncthreads();
#pragma unroll
  for (int i = 0; i < 32; i += 8)
    Wt[(size_t)(n0 + ty + i) * K + k0 + tx] = (_Float16)tile[tx][ty + i];
}

// ---------------- CSR aggregation, column-chunked + 8-way edge ILP ----------------
// One wave per (dst node, 64-col chunk); lane = column. Per-chunk random
// working set = 22400*64*2B = 2.87MB < 4MB L2/XCD -> gathers hit L2.
// 8 independent gathers in flight per loop trip to break the latency chain.

template<int ENT>
__global__ __launch_bounds__(256) void aggregate_k(const _Float16* __restrict__ x,
    const u32* __restrict__ off, const int* __restrict__ srcs,
    const float* __restrict__ dvo, const float* __restrict__ dvi,
    _Float16* __restrict__ out) {
  int wave = threadIdx.x >> 6;
  int lane = threadIdx.x & 63;
  int blk = blockIdx.x * 4 + wave;          // dst index (compact for ENT)
  int d;
  if (ENT) { int b = blk / 50; d = b * N_PER_B + 100 + (blk - b * 50); }
  else d = blk;
  int col = blockIdx.y * 64 + lane;
  u32 s0 = __builtin_amdgcn_readfirstlane(off[d]);
  u32 s1 = __builtin_amdgcn_readfirstlane(off[d + 1]);
  const _Float16* xc = x + col;
  float a0 = 0.f, a1 = 0.f, a2 = 0.f, a3 = 0.f;
  float a4 = 0.f, a5 = 0.f, a6 = 0.f, a7 = 0.f;
  u32 s = s0;
  for (; s + 8 <= s1; s += 8) {
    int i0 = __builtin_amdgcn_readfirstlane(srcs[s + 0]);
    int i1 = __builtin_amdgcn_readfirstlane(srcs[s + 1]);
    int i2 = __builtin_amdgcn_readfirstlane(srcs[s + 2]);
    int i3 = __builtin_amdgcn_readfirstlane(srcs[s + 3]);
    int i4 = __builtin_amdgcn_readfirstlane(srcs[s + 4]);
    int i5 = __builtin_amdgcn_readfirstlane(srcs[s + 5]);
    int i6 = __builtin_amdgcn_readfirstlane(srcs[s + 6]);
    int i7 = __builtin_amdgcn_readfirstlane(srcs[s + 7]);
    float w0 = dvo[i0], w1 = dvo[i1], w2 = dvo[i2], w3 = dvo[i3];
    float w4 = dvo[i4], w5 = dvo[i5], w6 = dvo[i6], w7 = dvo[i7];
    float v0 = (float)xc[(size_t)i0 * DCOL];
    float v1 = (float)xc[(size_t)i1 * DCOL];
    float v2 = (float)xc[(size_t)i2 * DCOL];
    float v3 = (float)xc[(size_t)i3 * DCOL];
    float v4 = (float)xc[(size_t)i4 * DCOL];
    float v5 = (float)xc[(size_t)i5 * DCOL];
    float v6 = (float)xc[(size_t)i6 * DCOL];
    float v7 = (float)xc[(size_t)i7 * DCOL];
    a0 += w0 * v0; a1 += w1 * v1; a2 += w2 * v2; a3 += w3 * v3;
    a4 += w4 * v4; a5 += w5 * v5; a6 += w6 * v6; a7 += w7 * v7;
  }
  for (; s < s1; ++s) {
    int i0 = __builtin_amdgcn_readfirstlane(srcs[s]);
    a0 += dvo[i0] * (float)xc[(size_t)i0 * DCOL];
  }
  float acc = ((a0 + a1) + (a2 + a3)) + ((a4 + a5) + (a6 + a7));
  out[(size_t)blk * DCOL + col] = (_Float16)(acc * dvi[d]);
}

// ---------------- MFMA GEMM: C = A[M,K] * Bt[N,K]^T (+bias, epilogue) ----------------
// EPI 0: leaky_relu(C+bias) -> f16 out (ld N) ; EPI 1: C+bias -> f32 out (ld N)

template<int EPI>
__global__ __launch_bounds__(256, 2) void gemm_bt(const _Float16* __restrict__ A,
    const _Float16* __restrict__ Bt, const float* __restrict__ bias,
    _Float16* __restrict__ outh, float* __restrict__ outf, int N, int K) {
  __shared__ __align__(16) _Float16 sA[128 * 32];
  __shared__ __align__(16) _Float16 sB[128 * 32];
  int tid = threadIdx.x;
  int wave = tid >> 6, lane = tid & 63;
  int wm = wave & 1, wn = wave >> 1;
  int lane16 = lane & 15, quad = lane >> 4;
  int m0 = blockIdx.y * 128, n0 = blockIdx.x * 128;
  int srow  = lane >> 2;          // 0..15
  int scolb = (lane & 3) * 16;    // byte offset within 64B row
  const char* aBase = (const char*)(A  + (size_t)(m0 + wave * 32 + srow) * K) + scolb;
  const char* bBase = (const char*)(Bt + (size_t)(n0 + wave * 32 + srow) * K) + scolb;
  const size_t rowSkip = (size_t)16 * K * sizeof(_Float16);
  _Float16* lA0 = &sA[(wave * 2 + 0) * 512];
  _Float16* lA1 = &sA[(wave * 2 + 1) * 512];
  _Float16* lB0 = &sB[(wave * 2 + 0) * 512];
  _Float16* lB1 = &sB[(wave * 2 + 1) * 512];

  f32x4 acc[4][4];
  f32x4 zero = {0.f, 0.f, 0.f, 0.f};
#pragma unroll
  for (int i = 0; i < 4; ++i)
#pragma unroll
    for (int j = 0; j < 4; ++j) acc[i][j] = zero;

  for (int k0 = 0; k0 < K; k0 += 32) {
    __syncthreads();
    size_t kb = (size_t)k0 * sizeof(_Float16);
    gload16(aBase + kb,           lA0);
    gload16(aBase + kb + rowSkip, lA1);
    gload16(bBase + kb,           lB0);
    gload16(bBase + kb + rowSkip, lB1);
    __syncthreads();  // drains vmcnt before any wave reads LDS
    h8 af[4], bq[4];
#pragma unroll
    for (int mt = 0; mt < 4; ++mt)
      af[mt] = *(const h8*)&sA[(wm * 64 + mt * 16 + lane16) * 32 + quad * 8];
#pragma unroll
    for (int nt = 0; nt < 4; ++nt)
      bq[nt] = *(const h8*)&sB[(wn * 64 + nt * 16 + lane16) * 32 + quad * 8];
#pragma unroll
    for (int mt = 0; mt < 4; ++mt)
#pragma unroll
      for (int nt = 0; nt < 4; ++nt)
        acc[mt][nt] = __builtin_amdgcn_mfma_f32_16x16x32_f16(af[mt], bq[nt], acc[mt][nt], 0, 0, 0);
  }

#pragma unroll
  for (int nt = 0; nt < 4; ++nt) {
    int n = n0 + wn * 64 + nt * 16 + lane16;
    float bv = bias[n];
#pragma unroll
    for (int mt = 0; mt < 4; ++mt) {
      int mb = m0 + wm * 64 + mt * 16 + quad * 4;  // C/D: row = quad*4+i, col = lane16
#pragma unroll
      for (int i = 0; i < 4; ++i) {
        float v = acc[mt][nt][i] + bv;
        if (EPI == 0) {
          v = (v > 0.f) ? v : 0.01f * v;
          outh[(size_t)(mb + i) * N + n] = (_Float16)v;
        } else {
          outf[(size_t)(mb + i) * N + n] = v;
        }
      }
    }
  }
}

// ---------------- launch ----------------

extern "C" void kernel_launch(void* const* d_in, const int* in_sizes, int n_in,
                              void* d_out, int out_size, void* d_ws, size_t ws_size,
                              hipStream_t stream) {
  const float* mh  = (const float*)d_in[0];
  const float* eh  = (const float*)d_in[1];
  const float* sh  = (const float*)d_in[2];
  const int*   es  = (const int*)d_in[3];
  const int*   ed  = (const int*)d_in[4];
  const float* te  = (const float*)d_in[5];
  const float* lns = (const float*)d_in[6];
  const float* lnb = (const float*)d_in[7];
  const float* gw  = (const float*)d_in[8];   // [3][1024][1024]
  const float* gb  = (const float*)d_in[9];   // [3][1024]
  const float* fw  = (const float*)d_in[10];  // [1024][768]
  const float* fb  = (const float*)d_in[11];  // [768]
  float* out = (float*)d_out;                 // [128*50*768] f32
  int nE = in_sizes[3];

  char* p = (char*)d_ws;
  auto alloc = [&](size_t bytes) -> void* {
    void* r = (void*)p;
    p += (bytes + 255) & ~(size_t)255;
    return r;
  };
  _Float16* xbuf = (_Float16*)alloc((size_t)NN * DCOL * 2);
  _Float16* agg  = (_Float16*)alloc((size_t)NN * DCOL * 2);
  _Float16* wt   = (_Float16*)alloc((size_t)3 * 1024 * 1024 * 2);
  _Float16* wtfc = (_Float16*)alloc((size_t)768 * 1024 * 2);
  u32* deg_out = (u32*)alloc((size_t)NN * 4);   // these three stay contiguous
  u32* deg_in  = (u32*)alloc((size_t)NN * 4);
  u32* cursor  = (u32*)alloc((size_t)NN * 4);
  u32* csr_off = (u32*)alloc((size_t)(NN + 1) * 4);
  float* dvo = (float*)alloc((size_t)NN * 4);
  float* dvi = (float*)alloc((size_t)NN * 4);
  int* csr_src = (int*)alloc((size_t)nE * 4);

  hipMemsetAsync(deg_out, 0, (size_t)3 * NN * 4, stream);  // deg_out, deg_in, cursor

  int eb = (nE + 255) / 256;
  degree_k<<<eb, 256, 0, stream>>>(es, ed, deg_out, deg_in, nE);
  dinv_k<<<(NN + 255) / 256, 256, 0, stream>>>(deg_out, deg_in, dvo, dvi);
  scan_k<<<1, 1024, 0, stream>>>(deg_in, csr_off, NN);
  scatter_k<<<eb, 256, 0, stream>>>(es, ed, csr_off, cursor, csr_src, nE);
  ln_k<<<NN, 256, 0, stream>>>(mh, eh, sh, te, lns, lnb, xbuf);
  transpose_k<<<dim3(32, 32), 256, 0, stream>>>(gw + 0 * 1048576, wt + 0 * 1048576, 1024, 1024);
  transpose_k<<<dim3(32, 32), 256, 0, stream>>>(gw + 1 * 1048576, wt + 1 * 1048576, 1024, 1024);
  transpose_k<<<dim3(32, 32), 256, 0, stream>>>(gw + 2 * 1048576, wt + 2 * 1048576, 1024, 1024);
  transpose_k<<<dim3(24, 32), 256, 0, stream>>>(fw, wtfc, 1024, 768);

  // layer 0
  aggregate_k<0><<<dim3(5600, 16), 256, 0, stream>>>(xbuf, csr_off, csr_src, dvo, dvi, agg);
  gemm_bt<0><<<dim3(8, 175), 256, 0, stream>>>(agg, wt + 0 * 1048576, gb + 0,    xbuf, nullptr, 1024, 1024);
  // layer 1
  aggregate_k<0><<<dim3(5600, 16), 256, 0, stream>>>(xbuf, csr_off, csr_src, dvo, dvi, agg);
  gemm_bt<0><<<dim3(8, 175), 256, 0, stream>>>(agg, wt + 1 * 1048576, gb + 1024, xbuf, nullptr, 1024, 1024);
  // layer 2: only entity dst rows consumed downstream -> compact 6400 rows
  aggregate_k<1><<<dim3(1600, 16), 256, 0, stream>>>(xbuf, csr_off, csr_src, dvo, dvi, agg);
  gemm_bt<0><<<dim3(8, 50), 256, 0, stream>>>(agg, wt + 2 * 1048576, gb + 2048, xbuf, nullptr, 1024, 1024);
  // FC on compact entity rows -> d_out [6400][768] f32
  gemm_bt<1><<<dim3(6, 50), 256, 0, stream>>>(xbuf, wtfc, fb, nullptr, out, 768, 1024);
}

// Round 4
// 858.195 us; speedup vs baseline: 2.5404x; 1.3529x over previous
//
#include <hip/hip_runtime.h>
#include <cstdint>

using u16 = unsigned short;
using u32 = unsigned int;

typedef _Float16 h8 __attribute__((ext_vector_type(8)));
typedef _Float16 h4 __attribute__((ext_vector_type(4)));
typedef float f32x4 __attribute__((ext_vector_type(4)));

#define N_PER_B 175
#define NN 22400
#define DCOL 1024

// async global->LDS, 16B per lane; LDS dst is wave-uniform base + lane*16
__device__ __forceinline__ void gload16(const void* g, void* l) {
  void* gnc = const_cast<void*>(g);
  __builtin_amdgcn_global_load_lds(
      (__attribute__((address_space(1))) unsigned int*)gnc,
      (__attribute__((address_space(3))) unsigned int*)l, 16, 0, 0);
}

// ---------------- degree / CSR build ----------------

__global__ void degree_k(const int* __restrict__ es, const int* __restrict__ ed,
                         u32* __restrict__ dout, u32* __restrict__ din, int nE) {
  int e = blockIdx.x * 256 + threadIdx.x;
  if (e < nE) {
    atomicAdd(&dout[es[e]], 1u);
    atomicAdd(&din[ed[e]], 1u);
  }
}

__global__ void dinv_k(const u32* __restrict__ dout, const u32* __restrict__ din,
                       float* __restrict__ vo, float* __restrict__ vi) {
  int i = blockIdx.x * 256 + threadIdx.x;
  if (i < NN) {
    u32 a = dout[i]; if (a == 0u) a = 1u;
    u32 b = din[i];  if (b == 0u) b = 1u;
    vo[i] = rsqrtf((float)a);
    vi[i] = rsqrtf((float)b);
  }
}

// single-block scan, wave-shuffle based: 2 barriers per 1024-chunk
__global__ __launch_bounds__(1024) void scan_k(const u32* __restrict__ deg,
                                               u32* __restrict__ off, int n) {
  __shared__ u32 wsum[16];
  __shared__ u32 carry_s;
  int tid = threadIdx.x;
  int lane = tid & 63, w = tid >> 6;
  if (tid == 0) carry_s = 0u;
  __syncthreads();
  for (int base = 0; base < n; base += 1024) {
    u32 cb = carry_s;
    int i = base + tid;
    u32 v = (i < n) ? deg[i] : 0u;
    u32 x = v;
#pragma unroll
    for (int o = 1; o < 64; o <<= 1) {
      u32 t = __shfl_up(x, o);
      if (lane >= o) x += t;
    }
    if (lane == 63) wsum[w] = x;
    __syncthreads();
    u32 woff = 0;
#pragma unroll
    for (int j = 0; j < 16; ++j) { u32 s = wsum[j]; if (j < w) woff += s; }
    u32 incl = cb + woff + x;
    if (i < n) off[i] = incl - v;          // exclusive
    if (tid == 1023) carry_s = incl;
    __syncthreads();
  }
  if (tid == 0) off[n] = carry_s;
}

__global__ void scatter_k(const int* __restrict__ es, const int* __restrict__ ed,
                          const u32* __restrict__ off, u32* __restrict__ cur,
                          int* __restrict__ csr, int nE) {
  int e = blockIdx.x * 256 + threadIdx.x;
  if (e < nE) {
    int d = ed[e];
    u32 p = atomicAdd(&cur[d], 1u);
    csr[off[d] + p] = es[e];
  }
}

// ---------------- concat + layernorm (+ *dvo) -> fp16 node matrix ----------------
// Output is PRE-SCALED by dinv_out: xs[n] = LN(x)[n] * dvo[n]; consumed only
// by aggregation, which then needs no per-edge weight.

__global__ __launch_bounds__(256) void ln_k(const float* __restrict__ mh,
    const float* __restrict__ eh, const float* __restrict__ sh,
    const float* __restrict__ te, const float* __restrict__ sc,
    const float* __restrict__ bi, const float* __restrict__ dvo,
    _Float16* __restrict__ x0) {
  int node = blockIdx.x;
  int b = node / N_PER_B;
  int p = node - b * N_PER_B;
  const float* row;
  int t;
  if (p < 100)      { row = mh + ((size_t)b * 100 + p) * 768;        t = 0; }
  else if (p < 150) { row = eh + ((size_t)b * 50 + (p - 100)) * 768; t = 1; }
  else              { row = sh + ((size_t)b * 25 + (p - 150)) * 768; t = 2; }
  int tid = threadIdx.x;
  const float* lp = (tid < 192) ? (row + tid * 4) : (te + t * 256 + (tid - 192) * 4);
  float4 v = *(const float4*)lp;
  float s = v.x + v.y + v.z + v.w;
  float q = v.x * v.x + v.y * v.y + v.z * v.z + v.w * v.w;
#pragma unroll
  for (int o = 32; o > 0; o >>= 1) { s += __shfl_down(s, o); q += __shfl_down(q, o); }
  __shared__ float red[8];
  int w = tid >> 6;
  if ((tid & 63) == 0) { red[w] = s; red[4 + w] = q; }
  __syncthreads();
  float ts = red[0] + red[1] + red[2] + red[3];
  float tq = red[4] + red[5] + red[6] + red[7];
  float mu = ts * (1.0f / 1024.0f);
  float var = tq * (1.0f / 1024.0f) - mu * mu;
  float r = rsqrtf(var + 1e-5f);
  float scale_o = dvo[node];
  int c = tid * 4;
  float4 g  = *(const float4*)(sc + c);
  float4 hb = *(const float4*)(bi + c);
  h4 o;
  o.x = (_Float16)(((v.x - mu) * r * g.x + hb.x) * scale_o);
  o.y = (_Float16)(((v.y - mu) * r * g.y + hb.y) * scale_o);
  o.z = (_Float16)(((v.z - mu) * r * g.z + hb.z) * scale_o);
  o.w = (_Float16)(((v.w - mu) * r * g.w + hb.w) * scale_o);
  *(h4*)(x0 + (size_t)node * DCOL + c) = o;
}

// ---------------- weight transpose fp32 [K][N] -> fp16 [N][K] ----------------

__global__ __launch_bounds__(256) void transpose_k(const float* __restrict__ W,
    _Float16* __restrict__ Wt, int K, int N) {
  __shared__ float tile[32][33];
  int n0 = blockIdx.x * 32, k0 = blockIdx.y * 32;
  int tx = threadIdx.x & 31, ty = threadIdx.x >> 5;  // 32 x 8
#pragma unroll
  for (int i = 0; i < 32; i += 8)
    tile[ty + i][tx] = W[(size_t)(k0 + ty + i) * N + n0 + tx];
  __syncthreads();
#pragma unroll
  for (int i = 0; i < 32; i += 8)
    Wt[(size_t)(n0 + ty + i) * K + k0 + tx] = (_Float16)tile[tx][ty + i];
}

// ---------------- CSR aggregation ----------------
// xs is pre-scaled by dvo. One wave per (dst, 64-col chunk); lane = col.
// agg[d] = dvi[d] * sum_src xs[src]
// - 64 edge indices fetched per vector load, extracted via readlane (no
//   per-trip index-load latency).
// - XCD-pinned chunks: blockIdx&7 selects XCD ~round-robin; XCD k handles
//   chunks k then k+8 -> per-XCD L2 working set = one 2.87MB chunk.

template<int ENT>
__global__ __launch_bounds__(256) void aggregate_k(const _Float16* __restrict__ xs,
    const u32* __restrict__ off, const int* __restrict__ srcs,
    const float* __restrict__ dvi, _Float16* __restrict__ out, int NG) {
  int wave = threadIdx.x >> 6;
  int lane = threadIdx.x & 63;
  int b = blockIdx.x;
  int xcd = b & 7;
  int idx = b >> 3;                 // [0, 2*NG)
  int half = (idx >= NG) ? 1 : 0;
  int grp = idx - half * NG;        // dst group [0, NG)
  int chunk = xcd + (half << 3);    // [0,16)
  int blk = grp * 4 + wave;         // compact dst index
  int d;
  if (ENT) { int bb = blk / 50; d = bb * N_PER_B + 100 + (blk - bb * 50); }
  else d = blk;
  int col = chunk * 64 + lane;
  u32 s0 = __builtin_amdgcn_readfirstlane(off[d]);
  u32 s1 = __builtin_amdgcn_readfirstlane(off[d + 1]);
  const _Float16* xc = xs + col;
  float a0 = 0.f, a1 = 0.f, a2 = 0.f, a3 = 0.f;
  float a4 = 0.f, a5 = 0.f, a6 = 0.f, a7 = 0.f;
  for (u32 base = s0; base < s1; base += 64) {
    u32 nrem = s1 - base;
    u32 iters = nrem < 64u ? nrem : 64u;
    // 64 indices in one coalesced-ish load (broadcast lines, L1/L2-hot)
    int sv = srcs[base + (lane < iters ? lane : 0u)];
    u32 j = 0;
    for (; j + 8 <= iters; j += 8) {
      int i0 = __builtin_amdgcn_readlane(sv, j + 0);
      int i1 = __builtin_amdgcn_readlane(sv, j + 1);
      int i2 = __builtin_amdgcn_readlane(sv, j + 2);
      int i3 = __builtin_amdgcn_readlane(sv, j + 3);
      int i4 = __builtin_amdgcn_readlane(sv, j + 4);
      int i5 = __builtin_amdgcn_readlane(sv, j + 5);
      int i6 = __builtin_amdgcn_readlane(sv, j + 6);
      int i7 = __builtin_amdgcn_readlane(sv, j + 7);
      float v0 = (float)xc[(size_t)i0 * DCOL];
      float v1 = (float)xc[(size_t)i1 * DCOL];
      float v2 = (float)xc[(size_t)i2 * DCOL];
      float v3 = (float)xc[(size_t)i3 * DCOL];
      float v4 = (float)xc[(size_t)i4 * DCOL];
      float v5 = (float)xc[(size_t)i5 * DCOL];
      float v6 = (float)xc[(size_t)i6 * DCOL];
      float v7 = (float)xc[(size_t)i7 * DCOL];
      a0 += v0; a1 += v1; a2 += v2; a3 += v3;
      a4 += v4; a5 += v5; a6 += v6; a7 += v7;
    }
    for (; j < iters; ++j) {
      int i0 = __builtin_amdgcn_readlane(sv, j);
      a0 += (float)xc[(size_t)i0 * DCOL];
    }
  }
  float acc = ((a0 + a1) + (a2 + a3)) + ((a4 + a5) + (a6 + a7));
  out[(size_t)blk * DCOL + col] = (_Float16)(acc * dvi[d]);
}

// ---------------- MFMA GEMM: C = A[M,K] * Bt[N,K]^T (+bias, epilogue) ----------------
// EPI 0: leaky_relu(C+bias)*dvo[row] -> f16 (feeds next aggregation)
// EPI 1: C+bias -> f32 (final FC output)
// EPI 2: leaky_relu(C+bias) -> f16 (layer-2 output feeding FC, unscaled)

template<int EPI>
__global__ __launch_bounds__(256, 2) void gemm_bt(const _Float16* __restrict__ A,
    const _Float16* __restrict__ Bt, const float* __restrict__ bias,
    const float* __restrict__ dvo,
    _Float16* __restrict__ outh, float* __restrict__ outf, int N, int K) {
  __shared__ __align__(16) _Float16 sA[128 * 32];
  __shared__ __align__(16) _Float16 sB[128 * 32];
  int tid = threadIdx.x;
  int wave = tid >> 6, lane = tid & 63;
  int wm = wave & 1, wn = wave >> 1;
  int lane16 = lane & 15, quad = lane >> 4;
  int m0 = blockIdx.y * 128, n0 = blockIdx.x * 128;
  int srow  = lane >> 2;          // 0..15
  int scolb = (lane & 3) * 16;    // byte offset within 64B row
  const char* aBase = (const char*)(A  + (size_t)(m0 + wave * 32 + srow) * K) + scolb;
  const char* bBase = (const char*)(Bt + (size_t)(n0 + wave * 32 + srow) * K) + scolb;
  const size_t rowSkip = (size_t)16 * K * sizeof(_Float16);
  _Float16* lA0 = &sA[(wave * 2 + 0) * 512];
  _Float16* lA1 = &sA[(wave * 2 + 1) * 512];
  _Float16* lB0 = &sB[(wave * 2 + 0) * 512];
  _Float16* lB1 = &sB[(wave * 2 + 1) * 512];

  f32x4 acc[4][4];
  f32x4 zero = {0.f, 0.f, 0.f, 0.f};
#pragma unroll
  for (int i = 0; i < 4; ++i)
#pragma unroll
    for (int j = 0; j < 4; ++j) acc[i][j] = zero;

  for (int k0 = 0; k0 < K; k0 += 32) {
    __syncthreads();
    size_t kb = (size_t)k0 * sizeof(_Float16);
    gload16(aBase + kb,           lA0);
    gload16(aBase + kb + rowSkip, lA1);
    gload16(bBase + kb,           lB0);
    gload16(bBase + kb + rowSkip, lB1);
    __syncthreads();  // drains vmcnt before any wave reads LDS
    h8 af[4], bq[4];
#pragma unroll
    for (int mt = 0; mt < 4; ++mt)
      af[mt] = *(const h8*)&sA[(wm * 64 + mt * 16 + lane16) * 32 + quad * 8];
#pragma unroll
    for (int nt = 0; nt < 4; ++nt)
      bq[nt] = *(const h8*)&sB[(wn * 64 + nt * 16 + lane16) * 32 + quad * 8];
#pragma unroll
    for (int mt = 0; mt < 4; ++mt)
#pragma unroll
      for (int nt = 0; nt < 4; ++nt)
        acc[mt][nt] = __builtin_amdgcn_mfma_f32_16x16x32_f16(af[mt], bq[nt], acc[mt][nt], 0, 0, 0);
  }

#pragma unroll
  for (int nt = 0; nt < 4; ++nt) {
    int n = n0 + wn * 64 + nt * 16 + lane16;
    float bv = bias[n];
#pragma unroll
    for (int mt = 0; mt < 4; ++mt) {
      int mb = m0 + wm * 64 + mt * 16 + quad * 4;  // C/D: row = quad*4+i, col = lane16
#pragma unroll
      for (int i = 0; i < 4; ++i) {
        float v = acc[mt][nt][i] + bv;
        if (EPI == 0) {
          v = (v > 0.f) ? v : 0.01f * v;
          v *= dvo[mb + i];
          outh[(size_t)(mb + i) * N + n] = (_Float16)v;
        } else if (EPI == 2) {
          v = (v > 0.f) ? v : 0.01f * v;
          outh[(size_t)(mb + i) * N + n] = (_Float16)v;
        } else {
          outf[(size_t)(mb + i) * N + n] = v;
        }
      }
    }
  }
}

// ---------------- launch ----------------

extern "C" void kernel_launch(void* const* d_in, const int* in_sizes, int n_in,
                              void* d_out, int out_size, void* d_ws, size_t ws_size,
                              hipStream_t stream) {
  const float* mh  = (const float*)d_in[0];
  const float* eh  = (const float*)d_in[1];
  const float* sh  = (const float*)d_in[2];
  const int*   es  = (const int*)d_in[3];
  const int*   ed  = (const int*)d_in[4];
  const float* te  = (const float*)d_in[5];
  const float* lns = (const float*)d_in[6];
  const float* lnb = (const float*)d_in[7];
  const float* gw  = (const float*)d_in[8];   // [3][1024][1024]
  const float* gb  = (const float*)d_in[9];   // [3][1024]
  const float* fw  = (const float*)d_in[10];  // [1024][768]
  const float* fb  = (const float*)d_in[11];  // [768]
  float* out = (float*)d_out;                 // [128*50*768] f32
  int nE = in_sizes[3];

  char* p = (char*)d_ws;
  auto alloc = [&](size_t bytes) -> void* {
    void* r = (void*)p;
    p += (bytes + 255) & ~(size_t)255;
    return r;
  };
  _Float16* xbuf = (_Float16*)alloc((size_t)NN * DCOL * 2);
  _Float16* agg  = (_Float16*)alloc((size_t)NN * DCOL * 2);
  _Float16* wt   = (_Float16*)alloc((size_t)3 * 1024 * 1024 * 2);
  _Float16* wtfc = (_Float16*)alloc((size_t)768 * 1024 * 2);
  u32* deg_out = (u32*)alloc((size_t)NN * 4);   // these three stay contiguous
  u32* deg_in  = (u32*)alloc((size_t)NN * 4);
  u32* cursor  = (u32*)alloc((size_t)NN * 4);
  u32* csr_off = (u32*)alloc((size_t)(NN + 1) * 4);
  float* dvo = (float*)alloc((size_t)NN * 4);
  float* dvi = (float*)alloc((size_t)NN * 4);
  int* csr_src = (int*)alloc((size_t)nE * 4);

  hipMemsetAsync(deg_out, 0, (size_t)3 * NN * 4, stream);  // deg_out, deg_in, cursor

  int eb = (nE + 255) / 256;
  degree_k<<<eb, 256, 0, stream>>>(es, ed, deg_out, deg_in, nE);
  dinv_k<<<(NN + 255) / 256, 256, 0, stream>>>(deg_out, deg_in, dvo, dvi);
  scan_k<<<1, 1024, 0, stream>>>(deg_in, csr_off, NN);
  scatter_k<<<eb, 256, 0, stream>>>(es, ed, csr_off, cursor, csr_src, nE);
  ln_k<<<NN, 256, 0, stream>>>(mh, eh, sh, te, lns, lnb, dvo, xbuf);
  transpose_k<<<dim3(32, 32), 256, 0, stream>>>(gw + 0 * 1048576, wt + 0 * 1048576, 1024, 1024);
  transpose_k<<<dim3(32, 32), 256, 0, stream>>>(gw + 1 * 1048576, wt + 1 * 1048576, 1024, 1024);
  transpose_k<<<dim3(32, 32), 256, 0, stream>>>(gw + 2 * 1048576, wt + 2 * 1048576, 1024, 1024);
  transpose_k<<<dim3(24, 32), 256, 0, stream>>>(fw, wtfc, 1024, 768);

  // layer 0  (xbuf is pre-scaled by dvo)
  aggregate_k<0><<<16 * 5600, 256, 0, stream>>>(xbuf, csr_off, csr_src, dvi, agg, 5600);
  gemm_bt<0><<<dim3(8, 175), 256, 0, stream>>>(agg, wt + 0 * 1048576, gb + 0,    dvo, xbuf, nullptr, 1024, 1024);
  // layer 1
  aggregate_k<0><<<16 * 5600, 256, 0, stream>>>(xbuf, csr_off, csr_src, dvi, agg, 5600);
  gemm_bt<0><<<dim3(8, 175), 256, 0, stream>>>(agg, wt + 1 * 1048576, gb + 1024, dvo, xbuf, nullptr, 1024, 1024);
  // layer 2: only entity dst rows consumed downstream -> compact 6400 rows, unscaled out
  aggregate_k<1><<<16 * 1600, 256, 0, stream>>>(xbuf, csr_off, csr_src, dvi, agg, 1600);
  gemm_bt<2><<<dim3(8, 50), 256, 0, stream>>>(agg, wt + 2 * 1048576, gb + 2048, nullptr, xbuf, nullptr, 1024, 1024);
  // FC on compact entity rows -> d_out [6400][768] f32
  gemm_bt<1><<<dim3(6, 50), 256, 0, stream>>>(xbuf, wtfc, fb, nullptr, nullptr, out, 768, 1024);
}

// Round 5
// 732.654 us; speedup vs baseline: 2.9757x; 1.1714x over previous
//
#include <hip/hip_runtime.h>
#include <cstdint>

using u16 = unsigned short;
using u32 = unsigned int;

typedef _Float16 h8 __attribute__((ext_vector_type(8)));
typedef _Float16 h4 __attribute__((ext_vector_type(4)));
typedef _Float16 h2 __attribute__((ext_vector_type(2)));
typedef float f32x4 __attribute__((ext_vector_type(4)));

#define N_PER_B 175
#define NN 22400
#define DCOL 1024

// async global->LDS, 16B per lane; LDS dst is wave-uniform base + lane*16
__device__ __forceinline__ void gload16(const void* g, void* l) {
  void* gnc = const_cast<void*>(g);
  __builtin_amdgcn_global_load_lds(
      (__attribute__((address_space(1))) unsigned int*)gnc,
      (__attribute__((address_space(3))) unsigned int*)l, 16, 0, 0);
}

// ---------------- degree / CSR build ----------------

__global__ void degree_k(const int* __restrict__ es, const int* __restrict__ ed,
                         u32* __restrict__ dout, u32* __restrict__ din, int nE) {
  int e = blockIdx.x * 256 + threadIdx.x;
  if (e < nE) {
    atomicAdd(&dout[es[e]], 1u);
    atomicAdd(&din[ed[e]], 1u);
  }
}

__global__ void dinv_k(const u32* __restrict__ dout, const u32* __restrict__ din,
                       float* __restrict__ vo, float* __restrict__ vi) {
  int i = blockIdx.x * 256 + threadIdx.x;
  if (i < NN) {
    u32 a = dout[i]; if (a == 0u) a = 1u;
    u32 b = din[i];  if (b == 0u) b = 1u;
    vo[i] = rsqrtf((float)a);
    vi[i] = rsqrtf((float)b);
  }
}

// single-block scan, wave-shuffle based: 2 barriers per 1024-chunk
__global__ __launch_bounds__(1024) void scan_k(const u32* __restrict__ deg,
                                               u32* __restrict__ off, int n) {
  __shared__ u32 wsum[16];
  __shared__ u32 carry_s;
  int tid = threadIdx.x;
  int lane = tid & 63, w = tid >> 6;
  if (tid == 0) carry_s = 0u;
  __syncthreads();
  for (int base = 0; base < n; base += 1024) {
    u32 cb = carry_s;
    int i = base + tid;
    u32 v = (i < n) ? deg[i] : 0u;
    u32 x = v;
#pragma unroll
    for (int o = 1; o < 64; o <<= 1) {
      u32 t = __shfl_up(x, o);
      if (lane >= o) x += t;
    }
    if (lane == 63) wsum[w] = x;
    __syncthreads();
    u32 woff = 0;
#pragma unroll
    for (int j = 0; j < 16; ++j) { u32 s = wsum[j]; if (j < w) woff += s; }
    u32 incl = cb + woff + x;
    if (i < n) off[i] = incl - v;          // exclusive
    if (tid == 1023) carry_s = incl;
    __syncthreads();
  }
  if (tid == 0) off[n] = carry_s;
}

__global__ void scatter_k(const int* __restrict__ es, const int* __restrict__ ed,
                          const u32* __restrict__ off, u32* __restrict__ cur,
                          int* __restrict__ csr, int nE) {
  int e = blockIdx.x * 256 + threadIdx.x;
  if (e < nE) {
    int d = ed[e];
    u32 p = atomicAdd(&cur[d], 1u);
    csr[off[d] + p] = es[e];
  }
}

// ---------------- concat + layernorm (+ *dvo) -> fp16 node matrix ----------------
// Output is PRE-SCALED by dinv_out: xs[n] = LN(x)[n] * dvo[n]; consumed only
// by aggregation, which then needs no per-edge weight.

__global__ __launch_bounds__(256) void ln_k(const float* __restrict__ mh,
    const float* __restrict__ eh, const float* __restrict__ sh,
    const float* __restrict__ te, const float* __restrict__ sc,
    const float* __restrict__ bi, const float* __restrict__ dvo,
    _Float16* __restrict__ x0) {
  int node = blockIdx.x;
  int b = node / N_PER_B;
  int p = node - b * N_PER_B;
  const float* row;
  int t;
  if (p < 100)      { row = mh + ((size_t)b * 100 + p) * 768;        t = 0; }
  else if (p < 150) { row = eh + ((size_t)b * 50 + (p - 100)) * 768; t = 1; }
  else              { row = sh + ((size_t)b * 25 + (p - 150)) * 768; t = 2; }
  int tid = threadIdx.x;
  const float* lp = (tid < 192) ? (row + tid * 4) : (te + t * 256 + (tid - 192) * 4);
  float4 v = *(const float4*)lp;
  float s = v.x + v.y + v.z + v.w;
  float q = v.x * v.x + v.y * v.y + v.z * v.z + v.w * v.w;
#pragma unroll
  for (int o = 32; o > 0; o >>= 1) { s += __shfl_down(s, o); q += __shfl_down(q, o); }
  __shared__ float red[8];
  int w = tid >> 6;
  if ((tid & 63) == 0) { red[w] = s; red[4 + w] = q; }
  __syncthreads();
  float ts = red[0] + red[1] + red[2] + red[3];
  float tq = red[4] + red[5] + red[6] + red[7];
  float mu = ts * (1.0f / 1024.0f);
  float var = tq * (1.0f / 1024.0f) - mu * mu;
  float r = rsqrtf(var + 1e-5f);
  float scale_o = dvo[node];
  int c = tid * 4;
  float4 g  = *(const float4*)(sc + c);
  float4 hb = *(const float4*)(bi + c);
  h4 o;
  o.x = (_Float16)(((v.x - mu) * r * g.x + hb.x) * scale_o);
  o.y = (_Float16)(((v.y - mu) * r * g.y + hb.y) * scale_o);
  o.z = (_Float16)(((v.z - mu) * r * g.z + hb.z) * scale_o);
  o.w = (_Float16)(((v.w - mu) * r * g.w + hb.w) * scale_o);
  *(h4*)(x0 + (size_t)node * DCOL + c) = o;
}

// ---------------- weight transpose fp32 [K][N] -> fp16 [N][K] ----------------

__global__ __launch_bounds__(256) void transpose_k(const float* __restrict__ W,
    _Float16* __restrict__ Wt, int K, int N) {
  __shared__ float tile[32][33];
  int n0 = blockIdx.x * 32, k0 = blockIdx.y * 32;
  int tx = threadIdx.x & 31, ty = threadIdx.x >> 5;  // 32 x 8
#pragma unroll
  for (int i = 0; i < 32; i += 8)
    tile[ty + i][tx] = W[(size_t)(k0 + ty + i) * N + n0 + tx];
  __syncthreads();
#pragma unroll
  for (int i = 0; i < 32; i += 8)
    Wt[(size_t)(n0 + ty + i) * K + k0 + tx] = (_Float16)tile[tx][ty + i];
}

// ---------------- CSR aggregation ----------------
// xs is pre-scaled by dvo. One wave per (dst, 128-col chunk); lane = col pair.
// agg[d] = dvi[d] * sum_src xs[src]
// - 64 edge indices per vector load, extracted via readlane.
// - Per edge-visit: one 4B v2f16 load + one v_pk_add_f16 (2 cols / 3 instr).
// - 8 packed accumulators (<=~8 fp16 adds each); final combine in fp32.
// - 8 chunks <-> 8 XCDs via blockIdx&7; per-XCD gather set 5.7MB (~70% in L2,
//   rest L3).

template<int ENT>
__global__ __launch_bounds__(256) void aggregate_k(const _Float16* __restrict__ xs,
    const u32* __restrict__ off, const int* __restrict__ srcs,
    const float* __restrict__ dvi, _Float16* __restrict__ out, int NG) {
  int wave = threadIdx.x >> 6;
  int lane = threadIdx.x & 63;
  int b = blockIdx.x;
  int chunk = b & 7;                // XCD-pinned chunk [0,8)
  int grp = b >> 3;                 // dst group [0, NG)
  int blk = grp * 4 + wave;         // compact dst index
  int d;
  if (ENT) { int bb = blk / 50; d = bb * N_PER_B + 100 + (blk - bb * 50); }
  else d = blk;
  u32 s0 = __builtin_amdgcn_readfirstlane(off[d]);
  u32 s1 = __builtin_amdgcn_readfirstlane(off[d + 1]);
  const h2* xc = (const h2*)xs + chunk * 64 + lane;   // pair column
  h2 c0 = (h2)0.f, c1 = (h2)0.f, c2 = (h2)0.f, c3 = (h2)0.f;
  h2 c4 = (h2)0.f, c5 = (h2)0.f, c6 = (h2)0.f, c7 = (h2)0.f;
  for (u32 base = s0; base < s1; base += 64) {
    u32 nrem = s1 - base;
    u32 iters = nrem < 64u ? nrem : 64u;
    int sv = srcs[base + (lane < iters ? lane : 0u)];
    u32 j = 0;
    for (; j + 8 <= iters; j += 8) {
      int i0 = __builtin_amdgcn_readlane(sv, j + 0);
      int i1 = __builtin_amdgcn_readlane(sv, j + 1);
      int i2 = __builtin_amdgcn_readlane(sv, j + 2);
      int i3 = __builtin_amdgcn_readlane(sv, j + 3);
      int i4 = __builtin_amdgcn_readlane(sv, j + 4);
      int i5 = __builtin_amdgcn_readlane(sv, j + 5);
      int i6 = __builtin_amdgcn_readlane(sv, j + 6);
      int i7 = __builtin_amdgcn_readlane(sv, j + 7);
      h2 v0 = xc[(size_t)i0 * 512];
      h2 v1 = xc[(size_t)i1 * 512];
      h2 v2 = xc[(size_t)i2 * 512];
      h2 v3 = xc[(size_t)i3 * 512];
      h2 v4 = xc[(size_t)i4 * 512];
      h2 v5 = xc[(size_t)i5 * 512];
      h2 v6 = xc[(size_t)i6 * 512];
      h2 v7 = xc[(size_t)i7 * 512];
      c0 += v0; c1 += v1; c2 += v2; c3 += v3;
      c4 += v4; c5 += v5; c6 += v6; c7 += v7;
    }
    for (; j < iters; ++j) {
      int i0 = __builtin_amdgcn_readlane(sv, j);
      c0 += xc[(size_t)i0 * 512];
    }
  }
  float wi = dvi[d];
  float lo = (((float)c0.x + (float)c1.x) + ((float)c2.x + (float)c3.x)) +
             (((float)c4.x + (float)c5.x) + ((float)c6.x + (float)c7.x));
  float hi = (((float)c0.y + (float)c1.y) + ((float)c2.y + (float)c3.y)) +
             (((float)c4.y + (float)c5.y) + ((float)c6.y + (float)c7.y));
  h2 r;
  r.x = (_Float16)(lo * wi);
  r.y = (_Float16)(hi * wi);
  *((h2*)(out + (size_t)blk * DCOL) + chunk * 64 + lane) = r;
}

// ---------------- MFMA GEMM: C = A[M,K] * Bt[N,K]^T (+bias, epilogue) ----------------
// EPI 0: leaky_relu(C+bias)*dvo[row] -> f16 (feeds next aggregation)
// EPI 1: C+bias -> f32 (final FC output)
// EPI 2: leaky_relu(C+bias) -> f16 (layer-2 output feeding FC, unscaled)

template<int EPI>
__global__ __launch_bounds__(256, 2) void gemm_bt(const _Float16* __restrict__ A,
    const _Float16* __restrict__ Bt, const float* __restrict__ bias,
    const float* __restrict__ dvo,
    _Float16* __restrict__ outh, float* __restrict__ outf, int N, int K) {
  __shared__ __align__(16) _Float16 sA[128 * 32];
  __shared__ __align__(16) _Float16 sB[128 * 32];
  int tid = threadIdx.x;
  int wave = tid >> 6, lane = tid & 63;
  int wm = wave & 1, wn = wave >> 1;
  int lane16 = lane & 15, quad = lane >> 4;
  int m0 = blockIdx.y * 128, n0 = blockIdx.x * 128;
  int srow  = lane >> 2;          // 0..15
  int scolb = (lane & 3) * 16;    // byte offset within 64B row
  const char* aBase = (const char*)(A  + (size_t)(m0 + wave * 32 + srow) * K) + scolb;
  const char* bBase = (const char*)(Bt + (size_t)(n0 + wave * 32 + srow) * K) + scolb;
  const size_t rowSkip = (size_t)16 * K * sizeof(_Float16);
  _Float16* lA0 = &sA[(wave * 2 + 0) * 512];
  _Float16* lA1 = &sA[(wave * 2 + 1) * 512];
  _Float16* lB0 = &sB[(wave * 2 + 0) * 512];
  _Float16* lB1 = &sB[(wave * 2 + 1) * 512];

  f32x4 acc[4][4];
  f32x4 zero = {0.f, 0.f, 0.f, 0.f};
#pragma unroll
  for (int i = 0; i < 4; ++i)
#pragma unroll
    for (int j = 0; j < 4; ++j) acc[i][j] = zero;

  for (int k0 = 0; k0 < K; k0 += 32) {
    __syncthreads();
    size_t kb = (size_t)k0 * sizeof(_Float16);
    gload16(aBase + kb,           lA0);
    gload16(aBase + kb + rowSkip, lA1);
    gload16(bBase + kb,           lB0);
    gload16(bBase + kb + rowSkip, lB1);
    __syncthreads();  // drains vmcnt before any wave reads LDS
    h8 af[4], bq[4];
#pragma unroll
    for (int mt = 0; mt < 4; ++mt)
      af[mt] = *(const h8*)&sA[(wm * 64 + mt * 16 + lane16) * 32 + quad * 8];
#pragma unroll
    for (int nt = 0; nt < 4; ++nt)
      bq[nt] = *(const h8*)&sB[(wn * 64 + nt * 16 + lane16) * 32 + quad * 8];
#pragma unroll
    for (int mt = 0; mt < 4; ++mt)
#pragma unroll
      for (int nt = 0; nt < 4; ++nt)
        acc[mt][nt] = __builtin_amdgcn_mfma_f32_16x16x32_f16(af[mt], bq[nt], acc[mt][nt], 0, 0, 0);
  }

#pragma unroll
  for (int nt = 0; nt < 4; ++nt) {
    int n = n0 + wn * 64 + nt * 16 + lane16;
    float bv = bias[n];
#pragma unroll
    for (int mt = 0; mt < 4; ++mt) {
      int mb = m0 + wm * 64 + mt * 16 + quad * 4;  // C/D: row = quad*4+i, col = lane16
#pragma unroll
      for (int i = 0; i < 4; ++i) {
        float v = acc[mt][nt][i] + bv;
        if (EPI == 0) {
          v = (v > 0.f) ? v : 0.01f * v;
          v *= dvo[mb + i];
          outh[(size_t)(mb + i) * N + n] = (_Float16)v;
        } else if (EPI == 2) {
          v = (v > 0.f) ? v : 0.01f * v;
          outh[(size_t)(mb + i) * N + n] = (_Float16)v;
        } else {
          outf[(size_t)(mb + i) * N + n] = v;
        }
      }
    }
  }
}

// ---------------- launch ----------------

extern "C" void kernel_launch(void* const* d_in, const int* in_sizes, int n_in,
                              void* d_out, int out_size, void* d_ws, size_t ws_size,
                              hipStream_t stream) {
  const float* mh  = (const float*)d_in[0];
  const float* eh  = (const float*)d_in[1];
  const float* sh  = (const float*)d_in[2];
  const int*   es  = (const int*)d_in[3];
  const int*   ed  = (const int*)d_in[4];
  const float* te  = (const float*)d_in[5];
  const float* lns = (const float*)d_in[6];
  const float* lnb = (const float*)d_in[7];
  const float* gw  = (const float*)d_in[8];   // [3][1024][1024]
  const float* gb  = (const float*)d_in[9];   // [3][1024]
  const float* fw  = (const float*)d_in[10];  // [1024][768]
  const float* fb  = (const float*)d_in[11];  // [768]
  float* out = (float*)d_out;                 // [128*50*768] f32
  int nE = in_sizes[3];

  char* p = (char*)d_ws;
  auto alloc = [&](size_t bytes) -> void* {
    void* r = (void*)p;
    p += (bytes + 255) & ~(size_t)255;
    return r;
  };
  _Float16* xbuf = (_Float16*)alloc((size_t)NN * DCOL * 2);
  _Float16* agg  = (_Float16*)alloc((size_t)NN * DCOL * 2);
  _Float16* wt   = (_Float16*)alloc((size_t)3 * 1024 * 1024 * 2);
  _Float16* wtfc = (_Float16*)alloc((size_t)768 * 1024 * 2);
  u32* deg_out = (u32*)alloc((size_t)NN * 4);   // these three stay contiguous
  u32* deg_in  = (u32*)alloc((size_t)NN * 4);
  u32* cursor  = (u32*)alloc((size_t)NN * 4);
  u32* csr_off = (u32*)alloc((size_t)(NN + 1) * 4);
  float* dvo = (float*)alloc((size_t)NN * 4);
  float* dvi = (float*)alloc((size_t)NN * 4);
  int* csr_src = (int*)alloc((size_t)nE * 4);

  hipMemsetAsync(deg_out, 0, (size_t)3 * NN * 4, stream);  // deg_out, deg_in, cursor

  int eb = (nE + 255) / 256;
  degree_k<<<eb, 256, 0, stream>>>(es, ed, deg_out, deg_in, nE);
  dinv_k<<<(NN + 255) / 256, 256, 0, stream>>>(deg_out, deg_in, dvo, dvi);
  scan_k<<<1, 1024, 0, stream>>>(deg_in, csr_off, NN);
  scatter_k<<<eb, 256, 0, stream>>>(es, ed, csr_off, cursor, csr_src, nE);
  ln_k<<<NN, 256, 0, stream>>>(mh, eh, sh, te, lns, lnb, dvo, xbuf);
  transpose_k<<<dim3(32, 32), 256, 0, stream>>>(gw + 0 * 1048576, wt + 0 * 1048576, 1024, 1024);
  transpose_k<<<dim3(32, 32), 256, 0, stream>>>(gw + 1 * 1048576, wt + 1 * 1048576, 1024, 1024);
  transpose_k<<<dim3(32, 32), 256, 0, stream>>>(gw + 2 * 1048576, wt + 2 * 1048576, 1024, 1024);
  transpose_k<<<dim3(24, 32), 256, 0, stream>>>(fw, wtfc, 1024, 768);

  // layer 0  (xbuf is pre-scaled by dvo)
  aggregate_k<0><<<8 * 5600, 256, 0, stream>>>(xbuf, csr_off, csr_src, dvi, agg, 5600);
  gemm_bt<0><<<dim3(8, 175), 256, 0, stream>>>(agg, wt + 0 * 1048576, gb + 0,    dvo, xbuf, nullptr, 1024, 1024);
  // layer 1
  aggregate_k<0><<<8 * 5600, 256, 0, stream>>>(xbuf, csr_off, csr_src, dvi, agg, 5600);
  gemm_bt<0><<<dim3(8, 175), 256, 0, stream>>>(agg, wt + 1 * 1048576, gb + 1024, dvo, xbuf, nullptr, 1024, 1024);
  // layer 2: only entity dst rows consumed downstream -> compact 6400 rows, unscaled out
  aggregate_k<1><<<8 * 1600, 256, 0, stream>>>(xbuf, csr_off, csr_src, dvi, agg, 1600);
  gemm_bt<2><<<dim3(8, 50), 256, 0, stream>>>(agg, wt + 2 * 1048576, gb + 2048, nullptr, xbuf, nullptr, 1024, 1024);
  // FC on compact entity rows -> d_out [6400][768] f32
  gemm_bt<1><<<dim3(6, 50), 256, 0, stream>>>(xbuf, wtfc, fb, nullptr, nullptr, out, 768, 1024);
}

// Round 6
// 707.544 us; speedup vs baseline: 3.0813x; 1.0355x over previous
//
#include <hip/hip_runtime.h>
#include <cstdint>

using u16 = unsigned short;
using u32 = unsigned int;

typedef _Float16 h8 __attribute__((ext_vector_type(8)));
typedef _Float16 h4 __attribute__((ext_vector_type(4)));
typedef _Float16 h2 __attribute__((ext_vector_type(2)));
typedef float f32x4 __attribute__((ext_vector_type(4)));

#define N_PER_B 175
#define NN 22400
#define DCOL 1024

// async global->LDS, 16B per lane; LDS dst is wave-uniform base + lane*16
__device__ __forceinline__ void gload16(const void* g, void* l) {
  void* gnc = const_cast<void*>(g);
  __builtin_amdgcn_global_load_lds(
      (__attribute__((address_space(1))) unsigned int*)gnc,
      (__attribute__((address_space(3))) unsigned int*)l, 16, 0, 0);
}

// ---------------- degree / CSR build ----------------

__global__ void degree_k(const int* __restrict__ es, const int* __restrict__ ed,
                         u32* __restrict__ dout, u32* __restrict__ din, int nE) {
  int e = blockIdx.x * 256 + threadIdx.x;
  if (e < nE) {
    atomicAdd(&dout[es[e]], 1u);
    atomicAdd(&din[ed[e]], 1u);
  }
}

__global__ void dinv_k(const u32* __restrict__ dout, const u32* __restrict__ din,
                       float* __restrict__ vo, float* __restrict__ vi) {
  int i = blockIdx.x * 256 + threadIdx.x;
  if (i < NN) {
    u32 a = dout[i]; if (a == 0u) a = 1u;
    u32 b = din[i];  if (b == 0u) b = 1u;
    vo[i] = rsqrtf((float)a);
    vi[i] = rsqrtf((float)b);
  }
}

// single-block scan, wave-shuffle based: 2 barriers per 1024-chunk
__global__ __launch_bounds__(1024) void scan_k(const u32* __restrict__ deg,
                                               u32* __restrict__ off, int n) {
  __shared__ u32 wsum[16];
  __shared__ u32 carry_s;
  int tid = threadIdx.x;
  int lane = tid & 63, w = tid >> 6;
  if (tid == 0) carry_s = 0u;
  __syncthreads();
  for (int base = 0; base < n; base += 1024) {
    u32 cb = carry_s;
    int i = base + tid;
    u32 v = (i < n) ? deg[i] : 0u;
    u32 x = v;
#pragma unroll
    for (int o = 1; o < 64; o <<= 1) {
      u32 t = __shfl_up(x, o);
      if (lane >= o) x += t;
    }
    if (lane == 63) wsum[w] = x;
    __syncthreads();
    u32 woff = 0;
#pragma unroll
    for (int j = 0; j < 16; ++j) { u32 s = wsum[j]; if (j < w) woff += s; }
    u32 incl = cb + woff + x;
    if (i < n) off[i] = incl - v;          // exclusive
    if (tid == 1023) carry_s = incl;
    __syncthreads();
  }
  if (tid == 0) off[n] = carry_s;
}

__global__ void scatter_k(const int* __restrict__ es, const int* __restrict__ ed,
                          const u32* __restrict__ off, u32* __restrict__ cur,
                          int* __restrict__ csr, int nE) {
  int e = blockIdx.x * 256 + threadIdx.x;
  if (e < nE) {
    int d = ed[e];
    u32 p = atomicAdd(&cur[d], 1u);
    csr[off[d] + p] = es[e];
  }
}

// ---------------- concat + layernorm (+ *dvo) -> fp16 node matrix ----------------
// Output is PRE-SCALED by dinv_out: xs[n] = LN(x)[n] * dvo[n]; consumed only
// by aggregation, which then needs no per-edge weight.

__global__ __launch_bounds__(256) void ln_k(const float* __restrict__ mh,
    const float* __restrict__ eh, const float* __restrict__ sh,
    const float* __restrict__ te, const float* __restrict__ sc,
    const float* __restrict__ bi, const float* __restrict__ dvo,
    _Float16* __restrict__ x0) {
  int node = blockIdx.x;
  int b = node / N_PER_B;
  int p = node - b * N_PER_B;
  const float* row;
  int t;
  if (p < 100)      { row = mh + ((size_t)b * 100 + p) * 768;        t = 0; }
  else if (p < 150) { row = eh + ((size_t)b * 50 + (p - 100)) * 768; t = 1; }
  else              { row = sh + ((size_t)b * 25 + (p - 150)) * 768; t = 2; }
  int tid = threadIdx.x;
  const float* lp = (tid < 192) ? (row + tid * 4) : (te + t * 256 + (tid - 192) * 4);
  float4 v = *(const float4*)lp;
  float s = v.x + v.y + v.z + v.w;
  float q = v.x * v.x + v.y * v.y + v.z * v.z + v.w * v.w;
#pragma unroll
  for (int o = 32; o > 0; o >>= 1) { s += __shfl_down(s, o); q += __shfl_down(q, o); }
  __shared__ float red[8];
  int w = tid >> 6;
  if ((tid & 63) == 0) { red[w] = s; red[4 + w] = q; }
  __syncthreads();
  float ts = red[0] + red[1] + red[2] + red[3];
  float tq = red[4] + red[5] + red[6] + red[7];
  float mu = ts * (1.0f / 1024.0f);
  float var = tq * (1.0f / 1024.0f) - mu * mu;
  float r = rsqrtf(var + 1e-5f);
  float scale_o = dvo[node];
  int c = tid * 4;
  float4 g  = *(const float4*)(sc + c);
  float4 hb = *(const float4*)(bi + c);
  h4 o;
  o.x = (_Float16)(((v.x - mu) * r * g.x + hb.x) * scale_o);
  o.y = (_Float16)(((v.y - mu) * r * g.y + hb.y) * scale_o);
  o.z = (_Float16)(((v.z - mu) * r * g.z + hb.z) * scale_o);
  o.w = (_Float16)(((v.w - mu) * r * g.w + hb.w) * scale_o);
  *(h4*)(x0 + (size_t)node * DCOL + c) = o;
}

// ---------------- weight transpose fp32 [K][N] -> fp16 [N][K] ----------------

__global__ __launch_bounds__(256) void transpose_k(const float* __restrict__ W,
    _Float16* __restrict__ Wt, int K, int N) {
  __shared__ float tile[32][33];
  int n0 = blockIdx.x * 32, k0 = blockIdx.y * 32;
  int tx = threadIdx.x & 31, ty = threadIdx.x >> 5;  // 32 x 8
#pragma unroll
  for (int i = 0; i < 32; i += 8)
    tile[ty + i][tx] = W[(size_t)(k0 + ty + i) * N + n0 + tx];
  __syncthreads();
#pragma unroll
  for (int i = 0; i < 32; i += 8)
    Wt[(size_t)(n0 + ty + i) * K + k0 + tx] = (_Float16)tile[tx][ty + i];
}

// ---------------- CSR aggregation ----------------
// xs is pre-scaled by dvo. One wave per (dst, 128-col chunk); lane = col pair.
// agg[d] = dvi[d] * sum_src xs[src]
// - 64 edge indices per vector load, extracted via readlane.
// - Per edge-visit: one 4B v2f16 load + one v_pk_add_f16.
// - 16-way unroll: 16 independent gathers in flight (MLP) per trip.
// - 8 chunks <-> 8 XCDs via blockIdx&7.

template<int ENT>
__global__ __launch_bounds__(256) void aggregate_k(const _Float16* __restrict__ xs,
    const u32* __restrict__ off, const int* __restrict__ srcs,
    const float* __restrict__ dvi, _Float16* __restrict__ out, int NG) {
  int wave = threadIdx.x >> 6;
  int lane = threadIdx.x & 63;
  int b = blockIdx.x;
  int chunk = b & 7;                // XCD-pinned chunk [0,8)
  int grp = b >> 3;                 // dst group [0, NG)
  int blk = grp * 4 + wave;         // compact dst index
  int d;
  if (ENT) { int bb = blk / 50; d = bb * N_PER_B + 100 + (blk - bb * 50); }
  else d = blk;
  u32 s0 = __builtin_amdgcn_readfirstlane(off[d]);
  u32 s1 = __builtin_amdgcn_readfirstlane(off[d + 1]);
  const h2* xc = (const h2*)xs + chunk * 64 + lane;   // pair column
  h2 c0 = (h2)0.f, c1 = (h2)0.f, c2 = (h2)0.f, c3 = (h2)0.f;
  h2 c4 = (h2)0.f, c5 = (h2)0.f, c6 = (h2)0.f, c7 = (h2)0.f;
  h2 c8 = (h2)0.f, c9 = (h2)0.f, cA = (h2)0.f, cB = (h2)0.f;
  h2 cC = (h2)0.f, cD = (h2)0.f, cE = (h2)0.f, cF = (h2)0.f;
  for (u32 base = s0; base < s1; base += 64) {
    u32 nrem = s1 - base;
    u32 iters = nrem < 64u ? nrem : 64u;
    int sv = srcs[base + (lane < iters ? lane : 0u)];
    u32 j = 0;
    for (; j + 16 <= iters; j += 16) {
      int i0 = __builtin_amdgcn_readlane(sv, j + 0);
      int i1 = __builtin_amdgcn_readlane(sv, j + 1);
      int i2 = __builtin_amdgcn_readlane(sv, j + 2);
      int i3 = __builtin_amdgcn_readlane(sv, j + 3);
      int i4 = __builtin_amdgcn_readlane(sv, j + 4);
      int i5 = __builtin_amdgcn_readlane(sv, j + 5);
      int i6 = __builtin_amdgcn_readlane(sv, j + 6);
      int i7 = __builtin_amdgcn_readlane(sv, j + 7);
      int i8 = __builtin_amdgcn_readlane(sv, j + 8);
      int i9 = __builtin_amdgcn_readlane(sv, j + 9);
      int iA = __builtin_amdgcn_readlane(sv, j + 10);
      int iB = __builtin_amdgcn_readlane(sv, j + 11);
      int iC = __builtin_amdgcn_readlane(sv, j + 12);
      int iD = __builtin_amdgcn_readlane(sv, j + 13);
      int iE = __builtin_amdgcn_readlane(sv, j + 14);
      int iF = __builtin_amdgcn_readlane(sv, j + 15);
      h2 v0 = xc[(size_t)i0 * 512];
      h2 v1 = xc[(size_t)i1 * 512];
      h2 v2 = xc[(size_t)i2 * 512];
      h2 v3 = xc[(size_t)i3 * 512];
      h2 v4 = xc[(size_t)i4 * 512];
      h2 v5 = xc[(size_t)i5 * 512];
      h2 v6 = xc[(size_t)i6 * 512];
      h2 v7 = xc[(size_t)i7 * 512];
      h2 v8 = xc[(size_t)i8 * 512];
      h2 v9 = xc[(size_t)i9 * 512];
      h2 vA = xc[(size_t)iA * 512];
      h2 vB = xc[(size_t)iB * 512];
      h2 vC = xc[(size_t)iC * 512];
      h2 vD = xc[(size_t)iD * 512];
      h2 vE = xc[(size_t)iE * 512];
      h2 vF = xc[(size_t)iF * 512];
      c0 += v0; c1 += v1; c2 += v2; c3 += v3;
      c4 += v4; c5 += v5; c6 += v6; c7 += v7;
      c8 += v8; c9 += v9; cA += vA; cB += vB;
      cC += vC; cD += vD; cE += vE; cF += vF;
    }
    for (; j + 4 <= iters; j += 4) {
      int i0 = __builtin_amdgcn_readlane(sv, j + 0);
      int i1 = __builtin_amdgcn_readlane(sv, j + 1);
      int i2 = __builtin_amdgcn_readlane(sv, j + 2);
      int i3 = __builtin_amdgcn_readlane(sv, j + 3);
      h2 v0 = xc[(size_t)i0 * 512];
      h2 v1 = xc[(size_t)i1 * 512];
      h2 v2 = xc[(size_t)i2 * 512];
      h2 v3 = xc[(size_t)i3 * 512];
      c0 += v0; c1 += v1; c2 += v2; c3 += v3;
    }
    for (; j < iters; ++j) {
      int i0 = __builtin_amdgcn_readlane(sv, j);
      c0 += xc[(size_t)i0 * 512];
    }
  }
  c0 += c8; c1 += c9; c2 += cA; c3 += cB;
  c4 += cC; c5 += cD; c6 += cE; c7 += cF;
  float wi = dvi[d];
  float lo = (((float)c0.x + (float)c1.x) + ((float)c2.x + (float)c3.x)) +
             (((float)c4.x + (float)c5.x) + ((float)c6.x + (float)c7.x));
  float hi = (((float)c0.y + (float)c1.y) + ((float)c2.y + (float)c3.y)) +
             (((float)c4.y + (float)c5.y) + ((float)c6.y + (float)c7.y));
  h2 r;
  r.x = (_Float16)(lo * wi);
  r.y = (_Float16)(hi * wi);
  *((h2*)(out + (size_t)blk * DCOL) + chunk * 64 + lane) = r;
}

// ---------------- MFMA GEMM: C = A[M,K] * Bt[N,K]^T (+bias, epilogue) ----------------
// EPI 0: leaky_relu(C+bias)*dvo[row] -> f16 (feeds next aggregation)
// EPI 1: C+bias -> f32 (final FC output)
// EPI 2: leaky_relu(C+bias) -> f16 (layer-2 output feeding FC, unscaled)
// launch_bounds (256,3): 3 blocks/CU -> better wave-level MFMA/VMEM overlap.

template<int EPI>
__global__ __launch_bounds__(256, 3) void gemm_bt(const _Float16* __restrict__ A,
    const _Float16* __restrict__ Bt, const float* __restrict__ bias,
    const float* __restrict__ dvo,
    _Float16* __restrict__ outh, float* __restrict__ outf, int N, int K) {
  __shared__ __align__(16) _Float16 sA[128 * 32];
  __shared__ __align__(16) _Float16 sB[128 * 32];
  int tid = threadIdx.x;
  int wave = tid >> 6, lane = tid & 63;
  int wm = wave & 1, wn = wave >> 1;
  int lane16 = lane & 15, quad = lane >> 4;
  int m0 = blockIdx.y * 128, n0 = blockIdx.x * 128;
  int srow  = lane >> 2;          // 0..15
  int scolb = (lane & 3) * 16;    // byte offset within 64B row
  const char* aBase = (const char*)(A  + (size_t)(m0 + wave * 32 + srow) * K) + scolb;
  const char* bBase = (const char*)(Bt + (size_t)(n0 + wave * 32 + srow) * K) + scolb;
  const size_t rowSkip = (size_t)16 * K * sizeof(_Float16);
  _Float16* lA0 = &sA[(wave * 2 + 0) * 512];
  _Float16* lA1 = &sA[(wave * 2 + 1) * 512];
  _Float16* lB0 = &sB[(wave * 2 + 0) * 512];
  _Float16* lB1 = &sB[(wave * 2 + 1) * 512];

  f32x4 acc[4][4];
  f32x4 zero = {0.f, 0.f, 0.f, 0.f};
#pragma unroll
  for (int i = 0; i < 4; ++i)
#pragma unroll
    for (int j = 0; j < 4; ++j) acc[i][j] = zero;

  for (int k0 = 0; k0 < K; k0 += 32) {
    __syncthreads();
    size_t kb = (size_t)k0 * sizeof(_Float16);
    gload16(aBase + kb,           lA0);
    gload16(aBase + kb + rowSkip, lA1);
    gload16(bBase + kb,           lB0);
    gload16(bBase + kb + rowSkip, lB1);
    __syncthreads();  // drains vmcnt before any wave reads LDS
    h8 af[4], bq[4];
#pragma unroll
    for (int mt = 0; mt < 4; ++mt)
      af[mt] = *(const h8*)&sA[(wm * 64 + mt * 16 + lane16) * 32 + quad * 8];
#pragma unroll
    for (int nt = 0; nt < 4; ++nt)
      bq[nt] = *(const h8*)&sB[(wn * 64 + nt * 16 + lane16) * 32 + quad * 8];
#pragma unroll
    for (int mt = 0; mt < 4; ++mt)
#pragma unroll
      for (int nt = 0; nt < 4; ++nt)
        acc[mt][nt] = __builtin_amdgcn_mfma_f32_16x16x32_f16(af[mt], bq[nt], acc[mt][nt], 0, 0, 0);
  }

#pragma unroll
  for (int nt = 0; nt < 4; ++nt) {
    int n = n0 + wn * 64 + nt * 16 + lane16;
    float bv = bias[n];
#pragma unroll
    for (int mt = 0; mt < 4; ++mt) {
      int mb = m0 + wm * 64 + mt * 16 + quad * 4;  // C/D: row = quad*4+i, col = lane16
#pragma unroll
      for (int i = 0; i < 4; ++i) {
        float v = acc[mt][nt][i] + bv;
        if (EPI == 0) {
          v = (v > 0.f) ? v : 0.01f * v;
          v *= dvo[mb + i];
          outh[(size_t)(mb + i) * N + n] = (_Float16)v;
        } else if (EPI == 2) {
          v = (v > 0.f) ? v : 0.01f * v;
          outh[(size_t)(mb + i) * N + n] = (_Float16)v;
        } else {
          outf[(size_t)(mb + i) * N + n] = v;
        }
      }
    }
  }
}

// ---------------- launch ----------------

extern "C" void kernel_launch(void* const* d_in, const int* in_sizes, int n_in,
                              void* d_out, int out_size, void* d_ws, size_t ws_size,
                              hipStream_t stream) {
  const float* mh  = (const float*)d_in[0];
  const float* eh  = (const float*)d_in[1];
  const float* sh  = (const float*)d_in[2];
  const int*   es  = (const int*)d_in[3];
  const int*   ed  = (const int*)d_in[4];
  const float* te  = (const float*)d_in[5];
  const float* lns = (const float*)d_in[6];
  const float* lnb = (const float*)d_in[7];
  const float* gw  = (const float*)d_in[8];   // [3][1024][1024]
  const float* gb  = (const float*)d_in[9];   // [3][1024]
  const float* fw  = (const float*)d_in[10];  // [1024][768]
  const float* fb  = (const float*)d_in[11];  // [768]
  float* out = (float*)d_out;                 // [128*50*768] f32
  int nE = in_sizes[3];

  char* p = (char*)d_ws;
  auto alloc = [&](size_t bytes) -> void* {
    void* r = (void*)p;
    p += (bytes + 255) & ~(size_t)255;
    return r;
  };
  _Float16* xbuf = (_Float16*)alloc((size_t)NN * DCOL * 2);
  _Float16* agg  = (_Float16*)alloc((size_t)NN * DCOL * 2);
  _Float16* wt   = (_Float16*)alloc((size_t)3 * 1024 * 1024 * 2);
  _Float16* wtfc = (_Float16*)alloc((size_t)768 * 1024 * 2);
  u32* deg_out = (u32*)alloc((size_t)NN * 4);   // these three stay contiguous
  u32* deg_in  = (u32*)alloc((size_t)NN * 4);
  u32* cursor  = (u32*)alloc((size_t)NN * 4);
  u32* csr_off = (u32*)alloc((size_t)(NN + 1) * 4);
  float* dvo = (float*)alloc((size_t)NN * 4);
  float* dvi = (float*)alloc((size_t)NN * 4);
  int* csr_src = (int*)alloc((size_t)nE * 4);

  hipMemsetAsync(deg_out, 0, (size_t)3 * NN * 4, stream);  // deg_out, deg_in, cursor

  int eb = (nE + 255) / 256;
  degree_k<<<eb, 256, 0, stream>>>(es, ed, deg_out, deg_in, nE);
  dinv_k<<<(NN + 255) / 256, 256, 0, stream>>>(deg_out, deg_in, dvo, dvi);
  scan_k<<<1, 1024, 0, stream>>>(deg_in, csr_off, NN);
  scatter_k<<<eb, 256, 0, stream>>>(es, ed, csr_off, cursor, csr_src, nE);
  ln_k<<<NN, 256, 0, stream>>>(mh, eh, sh, te, lns, lnb, dvo, xbuf);
  transpose_k<<<dim3(32, 32), 256, 0, stream>>>(gw + 0 * 1048576, wt + 0 * 1048576, 1024, 1024);
  transpose_k<<<dim3(32, 32), 256, 0, stream>>>(gw + 1 * 1048576, wt + 1 * 1048576, 1024, 1024);
  transpose_k<<<dim3(32, 32), 256, 0, stream>>>(gw + 2 * 1048576, wt + 2 * 1048576, 1024, 1024);
  transpose_k<<<dim3(24, 32), 256, 0, stream>>>(fw, wtfc, 1024, 768);

  // layer 0  (xbuf is pre-scaled by dvo)
  aggregate_k<0><<<8 * 5600, 256, 0, stream>>>(xbuf, csr_off, csr_src, dvi, agg, 5600);
  gemm_bt<0><<<dim3(8, 175), 256, 0, stream>>>(agg, wt + 0 * 1048576, gb + 0,    dvo, xbuf, nullptr, 1024, 1024);
  // layer 1
  aggregate_k<0><<<8 * 5600, 256, 0, stream>>>(xbuf, csr_off, csr_src, dvi, agg, 5600);
  gemm_bt<0><<<dim3(8, 175), 256, 0, stream>>>(agg, wt + 1 * 1048576, gb + 1024, dvo, xbuf, nullptr, 1024, 1024);
  // layer 2: only entity dst rows consumed downstream -> compact 6400 rows, unscaled out
  aggregate_k<1><<<8 * 1600, 256, 0, stream>>>(xbuf, csr_off, csr_src, dvi, agg, 1600);
  gemm_bt<2><<<dim3(8, 50), 256, 0, stream>>>(agg, wt + 2 * 1048576, gb + 2048, nullptr, xbuf, nullptr, 1024, 1024);
  // FC on compact entity rows -> d_out [6400][768] f32
  gemm_bt<1><<<dim3(6, 50), 256, 0, stream>>>(xbuf, wtfc, fb, nullptr, nullptr, out, 768, 1024);
}